// Round 9
// baseline (613.405 us; speedup 1.0000x reference)
//
#include <hip/hip_runtime.h>
#include <hip/hip_fp16.h>

#define USER_N 100000
#define ITEM_N 50000
#define NN (USER_N + ITEM_N)
#define D 64
#define IMGD 1024
#define LDP 68

#define BUCKET_BITS 10
#define BROWS (1 << BUCKET_BITS)
#define NBUCK ((NN + BROWS - 1) >> BUCKET_BITS)   // 147
#define CHUNK 4096

typedef _Float16 v4h __attribute__((ext_vector_type(4)));
typedef _Float16 v8h __attribute__((ext_vector_type(8)));
typedef float v4f __attribute__((ext_vector_type(4)));

// ---------- W transpose+cvt: Wt16[c][k] = (f16) W[k][c], once per call ------
__global__ __launch_bounds__(256) void wt_prep(
    const float* __restrict__ W, _Float16* __restrict__ Wt16)
{
    const int id = blockIdx.x * 256 + threadIdx.x;
    if (id >= D * IMGD) return;
    const int c = id >> 10;
    const int k = id & 1023;
    Wt16[id] = (_Float16)W[(size_t)k * D + c];
}

// ---------- MFMA GEMM: C[ITEM,64] = A[ITEM,1024] @ W[1024,64] + b -----------
// Block = 4 waves, tile 64x64. A fp32->f16 staged in LDS; B-frags read direct
// from global Wt16 (128 KB, L2-resident). fp32 accumulate via MFMA.
#define GAS 72   // LDS row stride in f16 (144 B: 8B-aligned, mild bank spread)
__global__ __launch_bounds__(256) void gemm_mfma(
    const float* __restrict__ A, const _Float16* __restrict__ Wt16,
    const float* __restrict__ b, float* __restrict__ C)
{
    __shared__ _Float16 Af[64][GAS];
    const int t = threadIdx.x;
    const int w = t >> 6;        // wave 0..3 -> rows w*16..w*16+15
    const int lane = t & 63;
    const int l16 = lane & 15;
    const int g = lane >> 4;     // k-group 0..3
    const int row0 = blockIdx.x * 64;

    v4f acc[4] = {};

    const int lr = t >> 4;         // loader row 0..15 (+16 steps)
    const int lk = (t & 15) * 4;   // loader k quad

    for (int k0 = 0; k0 < IMGD; k0 += 64) {
#pragma unroll
        for (int i = 0; i < 4; i++) {
            const int r = lr + i * 16;
            const int grow = row0 + r;
            float4 v = make_float4(0.f, 0.f, 0.f, 0.f);
            if (grow < ITEM_N)
                v = *reinterpret_cast<const float4*>(&A[(size_t)grow * IMGD + k0 + lk]);
            v4h h;
            h[0] = (_Float16)v.x; h[1] = (_Float16)v.y;
            h[2] = (_Float16)v.z; h[3] = (_Float16)v.w;
            *reinterpret_cast<v4h*>(&Af[r][lk]) = h;
        }
        __syncthreads();
#pragma unroll
        for (int s = 0; s < 2; s++) {
            const int kb = s * 32;
            union { v8h v; v4h h[2]; } af;
            af.h[0] = *reinterpret_cast<const v4h*>(&Af[w * 16 + l16][kb + g * 4]);
            af.h[1] = *reinterpret_cast<const v4h*>(&Af[w * 16 + l16][kb + 16 + g * 4]);
#pragma unroll
            for (int n = 0; n < 4; n++) {
                const _Float16* wp = Wt16 + (size_t)(n * 16 + l16) * IMGD + k0 + kb + g * 4;
                union { v8h v; v4h h[2]; } bf;
                bf.h[0] = *reinterpret_cast<const v4h*>(wp);
                bf.h[1] = *reinterpret_cast<const v4h*>(wp + 16);
                acc[n] = __builtin_amdgcn_mfma_f32_16x16x32_f16(af.v, bf.v, acc[n], 0, 0, 0);
            }
        }
        __syncthreads();
    }
    // C/D layout (m89-verified): col = lane&15, row = (lane>>4)*4 + reg
#pragma unroll
    for (int n = 0; n < 4; n++) {
        const int col = n * 16 + l16;
        const float bias = b[col];
#pragma unroll
        for (int r = 0; r < 4; r++) {
            const int grow = row0 + w * 16 + g * 4 + r;
            if (grow < ITEM_N)
                C[(size_t)grow * D + col] = acc[n][r] + bias;
        }
    }
}

// ------------- fp32 GEMM (fallback path, round-8 proven) --------------------
__global__ __launch_bounds__(256) void gemm_feats32(
    const float* __restrict__ A, const float* __restrict__ W,
    const float* __restrict__ b, float* __restrict__ C)
{
    __shared__ float As[32][LDP];
    __shared__ float Ws[64][LDP];
    const int row0 = blockIdx.x * 32;
    const int t = threadIdx.x;
    const int tx = t & 15, ty = t >> 4;
    float acc[2][4] = {};

    const int lr = t >> 4;
    const int lk = (t & 15) * 4;

    for (int k0 = 0; k0 < IMGD; k0 += 64) {
#pragma unroll
        for (int i = 0; i < 2; i++) {
            const int r = lr + i * 16;
            const int grow = row0 + r;
            float4 v = make_float4(0.f, 0.f, 0.f, 0.f);
            if (grow < ITEM_N)
                v = *reinterpret_cast<const float4*>(&A[(size_t)grow * IMGD + k0 + lk]);
            *reinterpret_cast<float4*>(&As[r][lk]) = v;
        }
#pragma unroll
        for (int i = 0; i < 4; i++) {
            const int kr = lr + i * 16;
            float4 v = *reinterpret_cast<const float4*>(&W[(size_t)(k0 + kr) * D + lk]);
            *reinterpret_cast<float4*>(&Ws[kr][lk]) = v;
        }
        __syncthreads();
#pragma unroll
        for (int kb = 0; kb < 16; kb++) {
            float a_[2][4], w_[4][4];
#pragma unroll
            for (int i = 0; i < 2; i++) {
                const float4 v = *reinterpret_cast<const float4*>(&As[ty * 2 + i][kb * 4]);
                a_[i][0] = v.x; a_[i][1] = v.y; a_[i][2] = v.z; a_[i][3] = v.w;
            }
#pragma unroll
            for (int j = 0; j < 4; j++) {
                const float4 v = *reinterpret_cast<const float4*>(&Ws[kb * 4 + j][tx * 4]);
                w_[j][0] = v.x; w_[j][1] = v.y; w_[j][2] = v.z; w_[j][3] = v.w;
            }
#pragma unroll
            for (int j = 0; j < 4; j++)
#pragma unroll
                for (int i = 0; i < 2; i++)
#pragma unroll
                    for (int c = 0; c < 4; c++)
                        acc[i][c] += a_[i][j] * w_[j][c];
        }
        __syncthreads();
    }
    const float4 bias = *reinterpret_cast<const float4*>(&b[tx * 4]);
#pragma unroll
    for (int i = 0; i < 2; i++) {
        const int grow = row0 + ty * 2 + i;
        if (grow < ITEM_N) {
            float4 v;
            v.x = acc[i][0] + bias.x;
            v.y = acc[i][1] + bias.y;
            v.z = acc[i][2] + bias.z;
            v.w = acc[i][3] + bias.w;
            *reinterpret_cast<float4*>(&C[(size_t)grow * D + tx * 4]) = v;
        }
    }
}

// ------------- Row L2 normalize -> fp16 output ------------------------------
__global__ __launch_bounds__(256) void rownorm_h(
    const float* __restrict__ X, __half* __restrict__ Y, int nrows)
{
    const int gid = blockIdx.x * blockDim.x + threadIdx.x;
    const int row = gid >> 6;
    const int lane = threadIdx.x & 63;
    if (row >= nrows) return;
    float v = X[(size_t)row * D + lane];
    float s = v * v;
#pragma unroll
    for (int o = 32; o > 0; o >>= 1) s += __shfl_xor(s, o, 64);
    const float scale = 1.0f / fmaxf(sqrtf(s), 1e-12f);
    Y[(size_t)row * D + lane] = __float2half(v * scale);
}

__global__ __launch_bounds__(256) void rownorm(float* __restrict__ X, int nrows)
{
    const int gid = blockIdx.x * blockDim.x + threadIdx.x;
    const int row = gid >> 6;
    const int lane = threadIdx.x & 63;
    if (row >= nrows) return;
    float v = X[(size_t)row * D + lane];
    float s = v * v;
#pragma unroll
    for (int o = 32; o > 0; o >>= 1) s += __shfl_xor(s, o, 64);
    const float scale = 1.0f / fmaxf(sqrtf(s), 1e-12f);
    X[(size_t)row * D + lane] = v * scale;
}

__global__ __launch_bounds__(256) void cvt_f2h(
    const float* __restrict__ s, __half* __restrict__ d, int n4)
{
    const int i = blockIdx.x * blockDim.x + threadIdx.x;
    if (i >= n4) return;
    const float4 v = reinterpret_cast<const float4*>(s)[i];
    __half2* d2 = reinterpret_cast<__half2*>(d);
    d2[2 * i]     = __floats2half2_rn(v.x, v.y);
    d2[2 * i + 1] = __floats2half2_rn(v.z, v.w);
}

// ============== CSR build via 2-level bucket sort (LDS atomics only) ========
__global__ __launch_bounds__(256) void bucket_count(
    const int* __restrict__ rows, int nnz, int nb, int* __restrict__ histT)
{
    __shared__ int cnt[NBUCK];
    for (int i = threadIdx.x; i < NBUCK; i += 256) cnt[i] = 0;
    __syncthreads();
    const int e0 = blockIdx.x * CHUNK;
    const int e1 = min(e0 + CHUNK, nnz);
    for (int e = e0 + threadIdx.x; e < e1; e += 256)
        atomicAdd(&cnt[rows[e] >> BUCKET_BITS], 1);
    __syncthreads();
    for (int b = threadIdx.x; b < NBUCK; b += 256)
        histT[b * nb + blockIdx.x] = cnt[b];
}

__global__ __launch_bounds__(1024) void scanA(
    const int* __restrict__ cnt, int* __restrict__ excl,
    int* __restrict__ blocksums, int n)
{
    const int t = threadIdx.x;
    const int gid = blockIdx.x * 1024 + t;
    const int lane = t & 63, wid = t >> 6;
    int v = (gid < n) ? cnt[gid] : 0;
    int x = v;
#pragma unroll
    for (int o = 1; o < 64; o <<= 1) {
        int y = __shfl_up(x, o, 64);
        if (lane >= o) x += y;
    }
    __shared__ int ws[16];
    __shared__ int wo[16];
    if (lane == 63) ws[wid] = x;
    __syncthreads();
    if (t < 16) {
        int s = ws[t];
        int xx = s;
#pragma unroll
        for (int o = 1; o < 16; o <<= 1) {
            int y = __shfl_up(xx, o, 16);
            if (t >= o) xx += y;
        }
        wo[t] = xx - s;
        if (t == 15) blocksums[blockIdx.x] = xx;
    }
    __syncthreads();
    if (gid < n) excl[gid] = x - v + wo[wid];
}

__global__ __launch_bounds__(1024) void scanB(int* __restrict__ bs, int nb)
{
    const int t = threadIdx.x;
    const int lane = t & 63, wid = t >> 6;
    int v = (t < nb) ? bs[t] : 0;
    int x = v;
#pragma unroll
    for (int o = 1; o < 64; o <<= 1) {
        int y = __shfl_up(x, o, 64);
        if (lane >= o) x += y;
    }
    __shared__ int ws[16];
    __shared__ int wo[16];
    if (lane == 63) ws[wid] = x;
    __syncthreads();
    if (t < 16) {
        int s = ws[t];
        int xx = s;
#pragma unroll
        for (int o = 1; o < 16; o <<= 1) {
            int y = __shfl_up(xx, o, 16);
            if (t >= o) xx += y;
        }
        wo[t] = xx - s;
    }
    __syncthreads();
    if (t < nb) bs[t] = x - v + wo[wid];
}

__global__ __launch_bounds__(256) void scan_apply(
    int* __restrict__ excl, const int* __restrict__ bo, int n)
{
    const int gid = blockIdx.x * blockDim.x + threadIdx.x;
    if (gid < n) excl[gid] += bo[gid >> 10];
}

__global__ __launch_bounds__(256) void bucket_place(
    const int* __restrict__ rows, const int* __restrict__ cols,
    const float* __restrict__ vals, int nnz, int nb,
    const int* __restrict__ offsT, uint2* __restrict__ rec)
{
    __shared__ int cur[NBUCK];
    for (int b = threadIdx.x; b < NBUCK; b += 256)
        cur[b] = offsT[b * nb + blockIdx.x];
    __syncthreads();
    const int e0 = blockIdx.x * CHUNK;
    const int e1 = min(e0 + CHUNK, nnz);
    for (int e = e0 + threadIdx.x; e < e1; e += 256) {
        const int r = rows[e];
        const int b = r >> BUCKET_BITS;
        const int pos = atomicAdd(&cur[b], 1);
        rec[pos] = make_uint2(((unsigned)cols[e] << BUCKET_BITS) |
                                  (unsigned)(r & (BROWS - 1)),
                              __float_as_uint(vals[e]));
    }
}

__global__ __launch_bounds__(1024) void bucket_finalize(
    const uint2* __restrict__ rec, int nnz, int nb,
    const int* __restrict__ offsT, int* __restrict__ rp,
    int2* __restrict__ ev)
{
    const int b = blockIdx.x;
    const int t = threadIdx.x;
    const int rlo = b << BUCKET_BITS;
    const int segs = offsT[b * nb];
    const int sege = (b + 1 < NBUCK) ? offsT[(b + 1) * nb] : nnz;

    __shared__ int cnt[BROWS];
    __shared__ int cur[BROWS];
    cnt[t] = 0;
    __syncthreads();
    for (int i = segs + t; i < sege; i += 1024)
        atomicAdd(&cnt[rec[i].x & (BROWS - 1)], 1);
    __syncthreads();

    const int lane = t & 63, wid = t >> 6;
    const int v = cnt[t];
    int x = v;
#pragma unroll
    for (int o = 1; o < 64; o <<= 1) {
        int y = __shfl_up(x, o, 64);
        if (lane >= o) x += y;
    }
    __shared__ int wsum[16];
    __shared__ int woff[16];
    if (lane == 63) wsum[wid] = x;
    __syncthreads();
    if (t < 16) {
        int s = wsum[t];
        int xx = s;
#pragma unroll
        for (int o = 1; o < 16; o <<= 1) {
            int y = __shfl_up(xx, o, 16);
            if (t >= o) xx += y;
        }
        woff[t] = xx - s;
    }
    __syncthreads();
    const int start = segs + (x - v + woff[wid]);

    if (rlo + t < NN) rp[rlo + t] = start;
    if (b == NBUCK - 1 && t == 0) rp[NN] = nnz;
    cur[t] = start;
    __syncthreads();

    for (int i = segs + t; i < sege; i += 1024) {
        const uint2 R = rec[i];
        const int rl = (int)(R.x & (BROWS - 1));
        const int c = (int)(R.x >> BUCKET_BITS);
        const int pos = atomicAdd(&cur[rl], 1);
        ev[pos] = make_int2(c, (int)R.y);
    }
}

// ------- CSR SPMM v4: 4 rows per wave (16 lanes x 8B per row) ---------------
__global__ __launch_bounds__(256) void spmm_h4(
    const int* __restrict__ rp, const int2* __restrict__ ev,
    const __half* __restrict__ src,
    float* __restrict__ out32, __half* __restrict__ out16, int limit16,
    const float* __restrict__ add1, const float* __restrict__ add2)
{
    const int wid = (blockIdx.x * 256 + threadIdx.x) >> 6;
    const int lane = threadIdx.x & 63;
    const int sub = lane >> 4;
    const int l16 = lane & 15;
    const int rowbase = wid * 4;
    if (rowbase >= NN) return;
    const int row = rowbase + sub;

    int v = 0;
    if (lane <= 4 && rowbase + lane <= NN) v = rp[rowbase + lane];
    const int s = __shfl(v, sub, 64);
    const int e = __shfl(v, sub + 1, 64);

    const __half* srcl = src + l16 * 4;
    float4 acc = make_float4(0.f, 0.f, 0.f, 0.f);

    union cvt { unsigned u; __half2 h; };
    int i = s;
    for (; i + 3 < e; i += 4) {
        const int2 E0 = ev[i], E1 = ev[i + 1], E2 = ev[i + 2], E3 = ev[i + 3];
        const uint2 g0 = *reinterpret_cast<const uint2*>(srcl + (size_t)E0.x * D);
        const uint2 g1 = *reinterpret_cast<const uint2*>(srcl + (size_t)E1.x * D);
        const uint2 g2 = *reinterpret_cast<const uint2*>(srcl + (size_t)E2.x * D);
        const uint2 g3 = *reinterpret_cast<const uint2*>(srcl + (size_t)E3.x * D);
#pragma unroll
        for (int k = 0; k < 4; k++) {
            const uint2 g = k == 0 ? g0 : k == 1 ? g1 : k == 2 ? g2 : g3;
            const float w = __int_as_float(k == 0 ? E0.y : k == 1 ? E1.y
                                           : k == 2 ? E2.y : E3.y);
            cvt c0, c1; c0.u = g.x; c1.u = g.y;
            const float2 f0 = __half22float2(c0.h);
            const float2 f1 = __half22float2(c1.h);
            acc.x += w * f0.x;
            acc.y += w * f0.y;
            acc.z += w * f1.x;
            acc.w += w * f1.y;
        }
    }
    for (; i < e; i++) {
        const int2 E0 = ev[i];
        const uint2 g = *reinterpret_cast<const uint2*>(srcl + (size_t)E0.x * D);
        const float w = __int_as_float(E0.y);
        cvt c0, c1; c0.u = g.x; c1.u = g.y;
        const float2 f0 = __half22float2(c0.h);
        const float2 f1 = __half22float2(c1.h);
        acc.x += w * f0.x;
        acc.y += w * f0.y;
        acc.z += w * f1.x;
        acc.w += w * f1.y;
    }

    if (row >= NN) return;
    const size_t idx = (size_t)row * D + l16 * 4;
    if (add1) {
        const float4 a = *reinterpret_cast<const float4*>(&add1[idx]);
        acc.x += a.x; acc.y += a.y; acc.z += a.z; acc.w += a.w;
    }
    if (add2) {
        const float4 a = *reinterpret_cast<const float4*>(&add2[idx]);
        acc.x += a.x; acc.y += a.y; acc.z += a.z; acc.w += a.w;
    }
    *reinterpret_cast<float4*>(&out32[idx]) = acc;
    if (row < limit16) {
        const __half2 o0 = __floats2half2_rn(acc.x, acc.y);
        const __half2 o1 = __floats2half2_rn(acc.z, acc.w);
        cvt c0, c1; c0.h = o0; c1.h = o1;
        *reinterpret_cast<uint2*>(&out16[idx]) = make_uint2(c0.u, c1.u);
    }
}

// ---------------- fp32 CSR SPMM (fallback path) -----------------------------
__global__ __launch_bounds__(256) void spmm_csr(
    const int* __restrict__ rp, const int2* __restrict__ ev,
    const float* __restrict__ srcU, const float* __restrict__ srcI,
    float* __restrict__ out,
    const float* __restrict__ add1, const float* __restrict__ add2)
{
    const int gid = blockIdx.x * blockDim.x + threadIdx.x;
    const int row = gid >> 6;
    const int lane = threadIdx.x & 63;
    if (row >= NN) return;
    const int s = rp[row], e = rp[row + 1];
    float acc = 0.f;
    int i = s;
    for (; i + 3 < e; i += 4) {
        const int2 e0 = ev[i], e1 = ev[i + 1], e2 = ev[i + 2], e3 = ev[i + 3];
        const float* p0 = (e0.x < USER_N) ? (srcU + (size_t)e0.x * D)
                                          : (srcI + (size_t)(e0.x - USER_N) * D);
        const float* p1 = (e1.x < USER_N) ? (srcU + (size_t)e1.x * D)
                                          : (srcI + (size_t)(e1.x - USER_N) * D);
        const float* p2 = (e2.x < USER_N) ? (srcU + (size_t)e2.x * D)
                                          : (srcI + (size_t)(e2.x - USER_N) * D);
        const float* p3 = (e3.x < USER_N) ? (srcU + (size_t)e3.x * D)
                                          : (srcI + (size_t)(e3.x - USER_N) * D);
        acc += __int_as_float(e0.y) * p0[lane];
        acc += __int_as_float(e1.y) * p1[lane];
        acc += __int_as_float(e2.y) * p2[lane];
        acc += __int_as_float(e3.y) * p3[lane];
    }
    for (; i < e; i++) {
        const int2 e0 = ev[i];
        const float* p0 = (e0.x < USER_N) ? (srcU + (size_t)e0.x * D)
                                          : (srcI + (size_t)(e0.x - USER_N) * D);
        acc += __int_as_float(e0.y) * p0[lane];
    }
    const size_t idx = (size_t)row * D + lane;
    if (add1) acc += add1[idx];
    if (add2) acc += add2[idx];
    out[idx] = acc;
}

extern "C" void kernel_launch(void* const* d_in, const int* in_sizes, int n_in,
                              void* d_out, int out_size, void* d_ws, size_t ws_size,
                              hipStream_t stream)
{
    const int*   adj_rows = (const int*)d_in[0];
    const int*   adj_cols = (const int*)d_in[1];
    const float* adj_vals = (const float*)d_in[2];
    const int*   img_rows = (const int*)d_in[3];
    const int*   img_cols = (const int*)d_in[4];
    const float* img_vals = (const float*)d_in[5];
    const float* img_emb  = (const float*)d_in[6];
    const float* uEmb     = (const float*)d_in[7];
    const float* iEmb     = (const float*)d_in[8];
    const float* Wt       = (const float*)d_in[9];
    const float* bt       = (const float*)d_in[10];
    float* out = (float*)d_out;

    const int e_adj = in_sizes[0];
    const int e_img = in_sizes[3];
    const int e_max = e_adj > e_img ? e_adj : e_img;
    const int NB_adj = (e_adj + CHUNK - 1) / CHUNK;
    const int NB_img = (e_img + CHUNK - 1) / CHUNK;
    const int NB_max = NB_adj > NB_img ? NB_adj : NB_img;

    const size_t ndbytes = (size_t)NN * D * sizeof(float);
    const size_t nhbytes = (size_t)NN * D * sizeof(__half);

    // ---- workspace layout (aliased: rec->xC, evImg->xB) ----
    size_t off = 0;
    auto carve = [&](size_t bytes) { size_t p = off; off += (bytes + 255) & ~(size_t)255; return p; };
    char* base = (char*)d_ws;
    const size_t o_featsN = carve((size_t)ITEM_N * D * sizeof(float));
    const size_t o_bufA   = carve(ndbytes);
    const size_t o_bufB   = carve(ndbytes);
    const size_t o_rpAdj  = carve((NN + 1) * sizeof(int));
    const size_t o_rpImg  = carve((NN + 1) * sizeof(int));
    const size_t o_bsums  = carve(1024 * sizeof(int));
    const size_t o_histT  = carve((size_t)NBUCK * NB_max * sizeof(int));
    const size_t o_rec    = carve((size_t)e_max * sizeof(uint2) > nhbytes
                                      ? (size_t)e_max * sizeof(uint2) : nhbytes);
    const size_t o_evAdj  = carve((size_t)e_adj * sizeof(int2));
    const size_t need_base = off;
    const size_t o_evImg  = carve((size_t)e_img * sizeof(int2) > nhbytes
                                      ? (size_t)e_img * sizeof(int2) : nhbytes);
    const size_t o_x0     = carve(nhbytes);
    const size_t o_wt16   = carve((size_t)D * IMGD * sizeof(_Float16));
    const size_t need_h = off;

    if (ws_size < need_base) return;
    const bool use_h = (ws_size >= need_h);

    float* featsN = (float*)(base + o_featsN);
    float* bufA   = (float*)(base + o_bufA);
    float* bufB   = (float*)(base + o_bufB);
    int* rpAdj    = (int*)(base + o_rpAdj);
    int* rpImg    = (int*)(base + o_rpImg);
    int* bsums    = (int*)(base + o_bsums);
    int* histT    = (int*)(base + o_histT);
    uint2* rec    = (uint2*)(base + o_rec);
    int2* evAdj   = (int2*)(base + o_evAdj);
    int2* evImg   = (int2*)(base + o_evImg);
    __half* xC    = (__half*)(base + o_rec);
    __half* xB    = (__half*)(base + o_evImg);
    __half* x0    = (__half*)(base + o_x0);
    _Float16* wt16 = (_Float16*)(base + o_wt16);

    // ---- build CSR for adj ----
    {
        const int n = NBUCK * NB_adj;
        const int nsb = (n + 1023) / 1024;
        bucket_count<<<NB_adj, 256, 0, stream>>>(adj_rows, e_adj, NB_adj, histT);
        scanA<<<nsb, 1024, 0, stream>>>(histT, histT, bsums, n);
        scanB<<<1, 1024, 0, stream>>>(bsums, nsb);
        scan_apply<<<(n + 255) / 256, 256, 0, stream>>>(histT, bsums, n);
        bucket_place<<<NB_adj, 256, 0, stream>>>(
            adj_rows, adj_cols, adj_vals, e_adj, NB_adj, histT, rec);
        bucket_finalize<<<NBUCK, 1024, 0, stream>>>(
            rec, e_adj, NB_adj, histT, rpAdj, evAdj);
    }
    // ---- build CSR for img ----
    {
        const int n = NBUCK * NB_img;
        const int nsb = (n + 1023) / 1024;
        bucket_count<<<NB_img, 256, 0, stream>>>(img_rows, e_img, NB_img, histT);
        scanA<<<nsb, 1024, 0, stream>>>(histT, histT, bsums, n);
        scanB<<<1, 1024, 0, stream>>>(bsums, nsb);
        scan_apply<<<(n + 255) / 256, 256, 0, stream>>>(histT, bsums, n);
        bucket_place<<<NB_img, 256, 0, stream>>>(
            img_rows, img_cols, img_vals, e_img, NB_img, histT, rec);
        bucket_finalize<<<NBUCK, 1024, 0, stream>>>(
            rec, e_img, NB_img, histT, rpImg, evImg);
    }

    const int SPMM4_GRID = (NN + 15) / 16;
    const int SPMM_GRID = (NN * 64 + 255) / 256;
    const int RN_GRID = (ITEM_N * 64 + 255) / 256;

    if (use_h) {
        __half* x0I = x0 + (size_t)USER_N * D;
        __half* xBI = xB + (size_t)USER_N * D;

        // x0 = [u16; i16]
        cvt_f2h<<<(USER_N * D / 4 + 255) / 256, 256, 0, stream>>>(
            uEmb, x0, USER_N * D / 4);
        cvt_f2h<<<(ITEM_N * D / 4 + 255) / 256, 256, 0, stream>>>(
            iEmb, x0I, ITEM_N * D / 4);

        // g = img_adj @ [u;i] -> bufA     (last reader of evImg)
        spmm_h4<<<SPMM4_GRID, 256, 0, stream>>>(
            rpImg, evImg, x0, bufA, nullptr, 0, nullptr, nullptr);

        // feats via MFMA; x0 item half <- normalized feats
        wt_prep<<<(D * IMGD + 255) / 256, 256, 0, stream>>>(Wt, wt16);
        gemm_mfma<<<(ITEM_N + 63) / 64, 256, 0, stream>>>(img_emb, wt16, bt, featsN);
        rownorm_h<<<RN_GRID, 256, 0, stream>>>(featsN, x0I, ITEM_N);

        // xB item half <- i16 (evImg region now dead)
        cvt_f2h<<<(ITEM_N * D / 4 + 255) / 256, 256, 0, stream>>>(
            iEmb, xBI, ITEM_N * D / 4);

        // e1 = adj @ x0 -> bufB; fp16 user rows -> xB  (xB = [e1_U; i16])
        spmm_h4<<<SPMM4_GRID, 256, 0, stream>>>(
            rpAdj, evAdj, x0, bufB, xB, USER_N, nullptr, nullptr);

        // E = adj @ xB + e1 + g -> bufA; fp16 -> xC
        spmm_h4<<<SPMM4_GRID, 256, 0, stream>>>(
            rpAdj, evAdj, xB, bufA, xC, NN, bufB, bufA);

        // cur1 = adj @ xC -> bufB; fp16 -> x0
        spmm_h4<<<SPMM4_GRID, 256, 0, stream>>>(
            rpAdj, evAdj, xC, bufB, x0, NN, nullptr, nullptr);

        // out = adj @ x0 + E + cur1
        spmm_h4<<<SPMM4_GRID, 256, 0, stream>>>(
            rpAdj, evAdj, x0, out, nullptr, 0, bufA, bufB);
    } else {
        gemm_feats32<<<(ITEM_N + 31) / 32, 256, 0, stream>>>(img_emb, Wt, bt, featsN);
        rownorm<<<RN_GRID, 256, 0, stream>>>(featsN, ITEM_N);

        spmm_csr<<<SPMM_GRID, 256, 0, stream>>>(
            rpImg, evImg, uEmb, iEmb, bufA, nullptr, nullptr);
        spmm_csr<<<SPMM_GRID, 256, 0, stream>>>(
            rpAdj, evAdj, uEmb, featsN, bufB, nullptr, nullptr);
        spmm_csr<<<SPMM_GRID, 256, 0, stream>>>(
            rpAdj, evAdj, bufB, iEmb, bufA, bufB, bufA);
        spmm_csr<<<SPMM_GRID, 256, 0, stream>>>(
            rpAdj, evAdj, bufA, bufA + (size_t)USER_N * D, bufB, nullptr, nullptr);
        spmm_csr<<<SPMM_GRID, 256, 0, stream>>>(
            rpAdj, evAdj, bufB, bufB + (size_t)USER_N * D, out, bufA, bufB);
    }
}

// Round 10
// 598.746 us; speedup vs baseline: 1.0245x; 1.0245x over previous
//
#include <hip/hip_runtime.h>
#include <hip/hip_fp16.h>

#define USER_N 100000
#define ITEM_N 50000
#define NN (USER_N + ITEM_N)
#define D 64
#define IMGD 1024
#define LDP 68

#define BUCKET_BITS 10
#define BROWS (1 << BUCKET_BITS)
#define NBUCK ((NN + BROWS - 1) >> BUCKET_BITS)   // 147
#define CHUNK 4096

typedef _Float16 v4h __attribute__((ext_vector_type(4)));
typedef _Float16 v8h __attribute__((ext_vector_type(8)));
typedef float v4f __attribute__((ext_vector_type(4)));

// ---------- W transpose+cvt: Wt16[c][k] = (f16) W[k][c], once per call ------
__global__ __launch_bounds__(256) void wt_prep(
    const float* __restrict__ W, _Float16* __restrict__ Wt16)
{
    const int id = blockIdx.x * 256 + threadIdx.x;
    if (id >= D * IMGD) return;
    const int c = id >> 10;
    const int k = id & 1023;
    Wt16[id] = (_Float16)W[(size_t)k * D + c];
}

// ---------- MFMA GEMM v2: 32-row tile, dbuf A, 2x2 wave split ---------------
// r9 post-mortem: 64-row tile was grid-limited (782 blocks, 29% occ) and the
// K-step chain (HBM A -> LDS -> bar -> L2 B -> MFMA -> bar) was fully serial.
// Here: 1563 blocks; next A-tile global loads issued BEFORE compute phase.
#define GAS2 68   // 136B row stride: b64 reads land on 16 distinct bank-pairs
__global__ __launch_bounds__(256) void gemm_mfma2(
    const float* __restrict__ A, const _Float16* __restrict__ Wt16,
    const float* __restrict__ b, float* __restrict__ C)
{
    __shared__ _Float16 Af[2][32][GAS2];
    const int t = threadIdx.x;
    const int w = t >> 6;
    const int lane = t & 63;
    const int l16 = lane & 15;
    const int g = lane >> 4;          // k-group 0..3
    const int row0 = blockIdx.x * 32;
    const int wr = (w >> 1) * 16;     // wave row half: 0 or 16
    const int wc = (w & 1) * 32;      // wave col half: 0 or 32

    v4f acc[2] = {};

    const int lrow0 = t >> 4;         // loader rows: t>>4 and t>>4 + 16
    const int lrow1 = lrow0 + 16;
    const int lk = (t & 15) * 4;
    const int ga0 = row0 + lrow0, ga1 = row0 + lrow1;

    // prologue: tile 0 -> buf 0
    {
        float4 v0 = make_float4(0.f, 0.f, 0.f, 0.f), v1 = v0;
        if (ga0 < ITEM_N) v0 = *reinterpret_cast<const float4*>(&A[(size_t)ga0 * IMGD + lk]);
        if (ga1 < ITEM_N) v1 = *reinterpret_cast<const float4*>(&A[(size_t)ga1 * IMGD + lk]);
        v4h h0, h1;
        h0[0] = (_Float16)v0.x; h0[1] = (_Float16)v0.y; h0[2] = (_Float16)v0.z; h0[3] = (_Float16)v0.w;
        h1[0] = (_Float16)v1.x; h1[1] = (_Float16)v1.y; h1[2] = (_Float16)v1.z; h1[3] = (_Float16)v1.w;
        *reinterpret_cast<v4h*>(&Af[0][lrow0][lk]) = h0;
        *reinterpret_cast<v4h*>(&Af[0][lrow1][lk]) = h1;
    }
    __syncthreads();

    for (int k0 = 0; k0 < IMGD; k0 += 64) {
        const int cur = (k0 >> 6) & 1;
        const bool has_next = (k0 + 64) < IMGD;
        // issue next-tile loads BEFORE compute: HBM latency hides under MFMA
        float4 n0 = make_float4(0.f, 0.f, 0.f, 0.f), n1 = n0;
        if (has_next) {
            if (ga0 < ITEM_N) n0 = *reinterpret_cast<const float4*>(&A[(size_t)ga0 * IMGD + k0 + 64 + lk]);
            if (ga1 < ITEM_N) n1 = *reinterpret_cast<const float4*>(&A[(size_t)ga1 * IMGD + k0 + 64 + lk]);
        }
#pragma unroll
        for (int s = 0; s < 2; s++) {
            const int kb = s * 32;
            union { v8h v; v4h h[2]; } af;
            af.h[0] = *reinterpret_cast<const v4h*>(&Af[cur][wr + l16][kb + g * 4]);
            af.h[1] = *reinterpret_cast<const v4h*>(&Af[cur][wr + l16][kb + 16 + g * 4]);
#pragma unroll
            for (int n = 0; n < 2; n++) {
                const _Float16* wp = Wt16 + (size_t)(wc + n * 16 + l16) * IMGD + k0 + kb + g * 4;
                union { v8h v; v4h h[2]; } bf;
                bf.h[0] = *reinterpret_cast<const v4h*>(wp);
                bf.h[1] = *reinterpret_cast<const v4h*>(wp + 16);
                acc[n] = __builtin_amdgcn_mfma_f32_16x16x32_f16(af.v, bf.v, acc[n], 0, 0, 0);
            }
        }
        if (has_next) {
            __syncthreads();
            v4h h0, h1;
            h0[0] = (_Float16)n0.x; h0[1] = (_Float16)n0.y; h0[2] = (_Float16)n0.z; h0[3] = (_Float16)n0.w;
            h1[0] = (_Float16)n1.x; h1[1] = (_Float16)n1.y; h1[2] = (_Float16)n1.z; h1[3] = (_Float16)n1.w;
            *reinterpret_cast<v4h*>(&Af[cur ^ 1][lrow0][lk]) = h0;
            *reinterpret_cast<v4h*>(&Af[cur ^ 1][lrow1][lk]) = h1;
            __syncthreads();
        }
    }
    // C/D layout (verified r9): col = lane&15, row = (lane>>4)*4 + reg
#pragma unroll
    for (int n = 0; n < 2; n++) {
        const int col = wc + n * 16 + l16;
        const float bias = b[col];
#pragma unroll
        for (int r = 0; r < 4; r++) {
            const int grow = row0 + wr + g * 4 + r;
            if (grow < ITEM_N)
                C[(size_t)grow * D + col] = acc[n][r] + bias;
        }
    }
}

// ------------- fp32 GEMM (fallback path) ------------------------------------
__global__ __launch_bounds__(256) void gemm_feats32(
    const float* __restrict__ A, const float* __restrict__ W,
    const float* __restrict__ b, float* __restrict__ C)
{
    __shared__ float As[32][LDP];
    __shared__ float Ws[64][LDP];
    const int row0 = blockIdx.x * 32;
    const int t = threadIdx.x;
    const int tx = t & 15, ty = t >> 4;
    float acc[2][4] = {};

    const int lr = t >> 4;
    const int lk = (t & 15) * 4;

    for (int k0 = 0; k0 < IMGD; k0 += 64) {
#pragma unroll
        for (int i = 0; i < 2; i++) {
            const int r = lr + i * 16;
            const int grow = row0 + r;
            float4 v = make_float4(0.f, 0.f, 0.f, 0.f);
            if (grow < ITEM_N)
                v = *reinterpret_cast<const float4*>(&A[(size_t)grow * IMGD + k0 + lk]);
            *reinterpret_cast<float4*>(&As[r][lk]) = v;
        }
#pragma unroll
        for (int i = 0; i < 4; i++) {
            const int kr = lr + i * 16;
            float4 v = *reinterpret_cast<const float4*>(&W[(size_t)(k0 + kr) * D + lk]);
            *reinterpret_cast<float4*>(&Ws[kr][lk]) = v;
        }
        __syncthreads();
#pragma unroll
        for (int kb = 0; kb < 16; kb++) {
            float a_[2][4], w_[4][4];
#pragma unroll
            for (int i = 0; i < 2; i++) {
                const float4 v = *reinterpret_cast<const float4*>(&As[ty * 2 + i][kb * 4]);
                a_[i][0] = v.x; a_[i][1] = v.y; a_[i][2] = v.z; a_[i][3] = v.w;
            }
#pragma unroll
            for (int j = 0; j < 4; j++) {
                const float4 v = *reinterpret_cast<const float4*>(&Ws[kb * 4 + j][tx * 4]);
                w_[j][0] = v.x; w_[j][1] = v.y; w_[j][2] = v.z; w_[j][3] = v.w;
            }
#pragma unroll
            for (int j = 0; j < 4; j++)
#pragma unroll
                for (int i = 0; i < 2; i++)
#pragma unroll
                    for (int c = 0; c < 4; c++)
                        acc[i][c] += a_[i][j] * w_[j][c];
        }
        __syncthreads();
    }
    const float4 bias = *reinterpret_cast<const float4*>(&b[tx * 4]);
#pragma unroll
    for (int i = 0; i < 2; i++) {
        const int grow = row0 + ty * 2 + i;
        if (grow < ITEM_N) {
            float4 v;
            v.x = acc[i][0] + bias.x;
            v.y = acc[i][1] + bias.y;
            v.z = acc[i][2] + bias.z;
            v.w = acc[i][3] + bias.w;
            *reinterpret_cast<float4*>(&C[(size_t)grow * D + tx * 4]) = v;
        }
    }
}

// ------------- Row L2 normalize -> fp16 output ------------------------------
__global__ __launch_bounds__(256) void rownorm_h(
    const float* __restrict__ X, __half* __restrict__ Y, int nrows)
{
    const int gid = blockIdx.x * blockDim.x + threadIdx.x;
    const int row = gid >> 6;
    const int lane = threadIdx.x & 63;
    if (row >= nrows) return;
    float v = X[(size_t)row * D + lane];
    float s = v * v;
#pragma unroll
    for (int o = 32; o > 0; o >>= 1) s += __shfl_xor(s, o, 64);
    const float scale = 1.0f / fmaxf(sqrtf(s), 1e-12f);
    Y[(size_t)row * D + lane] = __float2half(v * scale);
}

__global__ __launch_bounds__(256) void rownorm(float* __restrict__ X, int nrows)
{
    const int gid = blockIdx.x * blockDim.x + threadIdx.x;
    const int row = gid >> 6;
    const int lane = threadIdx.x & 63;
    if (row >= nrows) return;
    float v = X[(size_t)row * D + lane];
    float s = v * v;
#pragma unroll
    for (int o = 32; o > 0; o >>= 1) s += __shfl_xor(s, o, 64);
    const float scale = 1.0f / fmaxf(sqrtf(s), 1e-12f);
    X[(size_t)row * D + lane] = v * scale;
}

__global__ __launch_bounds__(256) void cvt_f2h(
    const float* __restrict__ s, __half* __restrict__ d, int n4)
{
    const int i = blockIdx.x * blockDim.x + threadIdx.x;
    if (i >= n4) return;
    const float4 v = reinterpret_cast<const float4*>(s)[i];
    __half2* d2 = reinterpret_cast<__half2*>(d);
    d2[2 * i]     = __floats2half2_rn(v.x, v.y);
    d2[2 * i + 1] = __floats2half2_rn(v.z, v.w);
}

// ============== CSR build via 2-level bucket sort (LDS atomics only) ========
__global__ __launch_bounds__(256) void bucket_count(
    const int* __restrict__ rows, int nnz, int nb, int* __restrict__ histT)
{
    __shared__ int cnt[NBUCK];
    for (int i = threadIdx.x; i < NBUCK; i += 256) cnt[i] = 0;
    __syncthreads();
    const int e0 = blockIdx.x * CHUNK;
    const int e1 = min(e0 + CHUNK, nnz);
    for (int e = e0 + threadIdx.x; e < e1; e += 256)
        atomicAdd(&cnt[rows[e] >> BUCKET_BITS], 1);
    __syncthreads();
    for (int b = threadIdx.x; b < NBUCK; b += 256)
        histT[b * nb + blockIdx.x] = cnt[b];
}

__global__ __launch_bounds__(1024) void scanA(
    const int* __restrict__ cnt, int* __restrict__ excl,
    int* __restrict__ blocksums, int n)
{
    const int t = threadIdx.x;
    const int gid = blockIdx.x * 1024 + t;
    const int lane = t & 63, wid = t >> 6;
    int v = (gid < n) ? cnt[gid] : 0;
    int x = v;
#pragma unroll
    for (int o = 1; o < 64; o <<= 1) {
        int y = __shfl_up(x, o, 64);
        if (lane >= o) x += y;
    }
    __shared__ int ws[16];
    __shared__ int wo[16];
    if (lane == 63) ws[wid] = x;
    __syncthreads();
    if (t < 16) {
        int s = ws[t];
        int xx = s;
#pragma unroll
        for (int o = 1; o < 16; o <<= 1) {
            int y = __shfl_up(xx, o, 16);
            if (t >= o) xx += y;
        }
        wo[t] = xx - s;
        if (t == 15) blocksums[blockIdx.x] = xx;
    }
    __syncthreads();
    if (gid < n) excl[gid] = x - v + wo[wid];
}

__global__ __launch_bounds__(1024) void scanB(int* __restrict__ bs, int nb)
{
    const int t = threadIdx.x;
    const int lane = t & 63, wid = t >> 6;
    int v = (t < nb) ? bs[t] : 0;
    int x = v;
#pragma unroll
    for (int o = 1; o < 64; o <<= 1) {
        int y = __shfl_up(x, o, 64);
        if (lane >= o) x += y;
    }
    __shared__ int ws[16];
    __shared__ int wo[16];
    if (lane == 63) ws[wid] = x;
    __syncthreads();
    if (t < 16) {
        int s = ws[t];
        int xx = s;
#pragma unroll
        for (int o = 1; o < 16; o <<= 1) {
            int y = __shfl_up(xx, o, 16);
            if (t >= o) xx += y;
        }
        wo[t] = xx - s;
    }
    __syncthreads();
    if (t < nb) bs[t] = x - v + wo[wid];
}

__global__ __launch_bounds__(256) void scan_apply(
    int* __restrict__ excl, const int* __restrict__ bo, int n)
{
    const int gid = blockIdx.x * blockDim.x + threadIdx.x;
    if (gid < n) excl[gid] += bo[gid >> 10];
}

__global__ __launch_bounds__(256) void bucket_place(
    const int* __restrict__ rows, const int* __restrict__ cols,
    const float* __restrict__ vals, int nnz, int nb,
    const int* __restrict__ offsT, uint2* __restrict__ rec)
{
    __shared__ int cur[NBUCK];
    for (int b = threadIdx.x; b < NBUCK; b += 256)
        cur[b] = offsT[b * nb + blockIdx.x];
    __syncthreads();
    const int e0 = blockIdx.x * CHUNK;
    const int e1 = min(e0 + CHUNK, nnz);
    for (int e = e0 + threadIdx.x; e < e1; e += 256) {
        const int r = rows[e];
        const int b = r >> BUCKET_BITS;
        const int pos = atomicAdd(&cur[b], 1);
        rec[pos] = make_uint2(((unsigned)cols[e] << BUCKET_BITS) |
                                  (unsigned)(r & (BROWS - 1)),
                              __float_as_uint(vals[e]));
    }
}

__global__ __launch_bounds__(1024) void bucket_finalize(
    const uint2* __restrict__ rec, int nnz, int nb,
    const int* __restrict__ offsT, int* __restrict__ rp,
    int2* __restrict__ ev)
{
    const int b = blockIdx.x;
    const int t = threadIdx.x;
    const int rlo = b << BUCKET_BITS;
    const int segs = offsT[b * nb];
    const int sege = (b + 1 < NBUCK) ? offsT[(b + 1) * nb] : nnz;

    __shared__ int cnt[BROWS];
    __shared__ int cur[BROWS];
    cnt[t] = 0;
    __syncthreads();
    for (int i = segs + t; i < sege; i += 1024)
        atomicAdd(&cnt[rec[i].x & (BROWS - 1)], 1);
    __syncthreads();

    const int lane = t & 63, wid = t >> 6;
    const int v = cnt[t];
    int x = v;
#pragma unroll
    for (int o = 1; o < 64; o <<= 1) {
        int y = __shfl_up(x, o, 64);
        if (lane >= o) x += y;
    }
    __shared__ int wsum[16];
    __shared__ int woff[16];
    if (lane == 63) wsum[wid] = x;
    __syncthreads();
    if (t < 16) {
        int s = wsum[t];
        int xx = s;
#pragma unroll
        for (int o = 1; o < 16; o <<= 1) {
            int y = __shfl_up(xx, o, 16);
            if (t >= o) xx += y;
        }
        woff[t] = xx - s;
    }
    __syncthreads();
    const int start = segs + (x - v + woff[wid]);

    if (rlo + t < NN) rp[rlo + t] = start;
    if (b == NBUCK - 1 && t == 0) rp[NN] = nnz;
    cur[t] = start;
    __syncthreads();

    for (int i = segs + t; i < sege; i += 1024) {
        const uint2 R = rec[i];
        const int rl = (int)(R.x & (BROWS - 1));
        const int c = (int)(R.x >> BUCKET_BITS);
        const int pos = atomicAdd(&cur[rl], 1);
        ev[pos] = make_int2(c, (int)R.y);
    }
}

// ------- CSR SPMM v5: 8 rows per wave (8 lanes x 16B per row) ---------------
// r7->r8: 4 rows/wave cut spmm 146 -> ~60us (row-chain count was the limiter).
// Same lever again: halve wave count, double gathers in flight per wave.
__global__ __launch_bounds__(256) void spmm_h8(
    const int* __restrict__ rp, const int2* __restrict__ ev,
    const __half* __restrict__ src,
    float* __restrict__ out32, __half* __restrict__ out16, int limit16,
    const float* __restrict__ add1, const float* __restrict__ add2)
{
    const int wid = (blockIdx.x * 256 + threadIdx.x) >> 6;
    const int lane = threadIdx.x & 63;
    const int sub = lane >> 3;       // row within wave: 0..7
    const int l8 = lane & 7;         // 8 lanes per row, 8 dims each
    const int rowbase = wid * 8;
    if (rowbase >= NN) return;
    const int row = rowbase + sub;

    int v = 0;
    if (lane <= 8 && rowbase + lane <= NN) v = rp[rowbase + lane];
    const int s = __shfl(v, sub, 64);
    const int e = __shfl(v, sub + 1, 64);

    const __half* srcl = src + l8 * 8;
    float acc[8] = {};

    union cvt4 { uint4 u; __half2 h[4]; };
    int i = s;
    for (; i + 3 < e; i += 4) {
        const int2 E0 = ev[i], E1 = ev[i + 1], E2 = ev[i + 2], E3 = ev[i + 3];
        cvt4 g0, g1, g2, g3;
        g0.u = *reinterpret_cast<const uint4*>(srcl + (size_t)E0.x * D);
        g1.u = *reinterpret_cast<const uint4*>(srcl + (size_t)E1.x * D);
        g2.u = *reinterpret_cast<const uint4*>(srcl + (size_t)E2.x * D);
        g3.u = *reinterpret_cast<const uint4*>(srcl + (size_t)E3.x * D);
#pragma unroll
        for (int k = 0; k < 4; k++) {
            const cvt4& g = k == 0 ? g0 : k == 1 ? g1 : k == 2 ? g2 : g3;
            const float w = __int_as_float(k == 0 ? E0.y : k == 1 ? E1.y
                                           : k == 2 ? E2.y : E3.y);
#pragma unroll
            for (int j = 0; j < 4; j++) {
                const float2 f = __half22float2(g.h[j]);
                acc[2 * j]     += w * f.x;
                acc[2 * j + 1] += w * f.y;
            }
        }
    }
    for (; i < e; i++) {
        const int2 E0 = ev[i];
        cvt4 g;
        g.u = *reinterpret_cast<const uint4*>(srcl + (size_t)E0.x * D);
        const float w = __int_as_float(E0.y);
#pragma unroll
        for (int j = 0; j < 4; j++) {
            const float2 f = __half22float2(g.h[j]);
            acc[2 * j]     += w * f.x;
            acc[2 * j + 1] += w * f.y;
        }
    }

    if (row >= NN) return;
    const size_t idx = (size_t)row * D + l8 * 8;
#pragma unroll
    for (int h = 0; h < 2; h++) {
        if (add1) {
            const float4 a = *reinterpret_cast<const float4*>(&add1[idx + h * 4]);
            acc[4 * h] += a.x; acc[4 * h + 1] += a.y;
            acc[4 * h + 2] += a.z; acc[4 * h + 3] += a.w;
        }
        if (add2) {
            const float4 a = *reinterpret_cast<const float4*>(&add2[idx + h * 4]);
            acc[4 * h] += a.x; acc[4 * h + 1] += a.y;
            acc[4 * h + 2] += a.z; acc[4 * h + 3] += a.w;
        }
        float4 o;
        o.x = acc[4 * h]; o.y = acc[4 * h + 1];
        o.z = acc[4 * h + 2]; o.w = acc[4 * h + 3];
        *reinterpret_cast<float4*>(&out32[idx + h * 4]) = o;
    }
    if (row < limit16) {
        cvt4 o16;
#pragma unroll
        for (int j = 0; j < 4; j++)
            o16.h[j] = __floats2half2_rn(acc[2 * j], acc[2 * j + 1]);
        *reinterpret_cast<uint4*>(&out16[idx]) = o16.u;
    }
}

// ---------------- fp32 CSR SPMM (fallback path) -----------------------------
__global__ __launch_bounds__(256) void spmm_csr(
    const int* __restrict__ rp, const int2* __restrict__ ev,
    const float* __restrict__ srcU, const float* __restrict__ srcI,
    float* __restrict__ out,
    const float* __restrict__ add1, const float* __restrict__ add2)
{
    const int gid = blockIdx.x * blockDim.x + threadIdx.x;
    const int row = gid >> 6;
    const int lane = threadIdx.x & 63;
    if (row >= NN) return;
    const int s = rp[row], e = rp[row + 1];
    float acc = 0.f;
    int i = s;
    for (; i + 3 < e; i += 4) {
        const int2 e0 = ev[i], e1 = ev[i + 1], e2 = ev[i + 2], e3 = ev[i + 3];
        const float* p0 = (e0.x < USER_N) ? (srcU + (size_t)e0.x * D)
                                          : (srcI + (size_t)(e0.x - USER_N) * D);
        const float* p1 = (e1.x < USER_N) ? (srcU + (size_t)e1.x * D)
                                          : (srcI + (size_t)(e1.x - USER_N) * D);
        const float* p2 = (e2.x < USER_N) ? (srcU + (size_t)e2.x * D)
                                          : (srcI + (size_t)(e2.x - USER_N) * D);
        const float* p3 = (e3.x < USER_N) ? (srcU + (size_t)e3.x * D)
                                          : (srcI + (size_t)(e3.x - USER_N) * D);
        acc += __int_as_float(e0.y) * p0[lane];
        acc += __int_as_float(e1.y) * p1[lane];
        acc += __int_as_float(e2.y) * p2[lane];
        acc += __int_as_float(e3.y) * p3[lane];
    }
    for (; i < e; i++) {
        const int2 e0 = ev[i];
        const float* p0 = (e0.x < USER_N) ? (srcU + (size_t)e0.x * D)
                                          : (srcI + (size_t)(e0.x - USER_N) * D);
        acc += __int_as_float(e0.y) * p0[lane];
    }
    const size_t idx = (size_t)row * D + lane;
    if (add1) acc += add1[idx];
    if (add2) acc += add2[idx];
    out[idx] = acc;
}

extern "C" void kernel_launch(void* const* d_in, const int* in_sizes, int n_in,
                              void* d_out, int out_size, void* d_ws, size_t ws_size,
                              hipStream_t stream)
{
    const int*   adj_rows = (const int*)d_in[0];
    const int*   adj_cols = (const int*)d_in[1];
    const float* adj_vals = (const float*)d_in[2];
    const int*   img_rows = (const int*)d_in[3];
    const int*   img_cols = (const int*)d_in[4];
    const float* img_vals = (const float*)d_in[5];
    const float* img_emb  = (const float*)d_in[6];
    const float* uEmb     = (const float*)d_in[7];
    const float* iEmb     = (const float*)d_in[8];
    const float* Wt       = (const float*)d_in[9];
    const float* bt       = (const float*)d_in[10];
    float* out = (float*)d_out;

    const int e_adj = in_sizes[0];
    const int e_img = in_sizes[3];
    const int e_max = e_adj > e_img ? e_adj : e_img;
    const int NB_adj = (e_adj + CHUNK - 1) / CHUNK;
    const int NB_img = (e_img + CHUNK - 1) / CHUNK;
    const int NB_max = NB_adj > NB_img ? NB_adj : NB_img;

    const size_t ndbytes = (size_t)NN * D * sizeof(float);
    const size_t nhbytes = (size_t)NN * D * sizeof(__half);

    // ---- workspace layout (aliased: rec->xC, evImg->xB) ----
    size_t off = 0;
    auto carve = [&](size_t bytes) { size_t p = off; off += (bytes + 255) & ~(size_t)255; return p; };
    char* base = (char*)d_ws;
    const size_t o_featsN = carve((size_t)ITEM_N * D * sizeof(float));
    const size_t o_bufA   = carve(ndbytes);
    const size_t o_bufB   = carve(ndbytes);
    const size_t o_rpAdj  = carve((NN + 1) * sizeof(int));
    const size_t o_rpImg  = carve((NN + 1) * sizeof(int));
    const size_t o_bsums  = carve(1024 * sizeof(int));
    const size_t o_histT  = carve((size_t)NBUCK * NB_max * sizeof(int));
    const size_t o_rec    = carve((size_t)e_max * sizeof(uint2) > nhbytes
                                      ? (size_t)e_max * sizeof(uint2) : nhbytes);
    const size_t o_evAdj  = carve((size_t)e_adj * sizeof(int2));
    const size_t need_base = off;
    const size_t o_evImg  = carve((size_t)e_img * sizeof(int2) > nhbytes
                                      ? (size_t)e_img * sizeof(int2) : nhbytes);
    const size_t o_x0     = carve(nhbytes);
    const size_t o_wt16   = carve((size_t)D * IMGD * sizeof(_Float16));
    const size_t need_h = off;

    if (ws_size < need_base) return;
    const bool use_h = (ws_size >= need_h);

    float* featsN = (float*)(base + o_featsN);
    float* bufA   = (float*)(base + o_bufA);
    float* bufB   = (float*)(base + o_bufB);
    int* rpAdj    = (int*)(base + o_rpAdj);
    int* rpImg    = (int*)(base + o_rpImg);
    int* bsums    = (int*)(base + o_bsums);
    int* histT    = (int*)(base + o_histT);
    uint2* rec    = (uint2*)(base + o_rec);
    int2* evAdj   = (int2*)(base + o_evAdj);
    int2* evImg   = (int2*)(base + o_evImg);
    __half* xC    = (__half*)(base + o_rec);
    __half* xB    = (__half*)(base + o_evImg);
    __half* x0    = (__half*)(base + o_x0);
    _Float16* wt16 = (_Float16*)(base + o_wt16);

    // ---- build CSR for adj ----
    {
        const int n = NBUCK * NB_adj;
        const int nsb = (n + 1023) / 1024;
        bucket_count<<<NB_adj, 256, 0, stream>>>(adj_rows, e_adj, NB_adj, histT);
        scanA<<<nsb, 1024, 0, stream>>>(histT, histT, bsums, n);
        scanB<<<1, 1024, 0, stream>>>(bsums, nsb);
        scan_apply<<<(n + 255) / 256, 256, 0, stream>>>(histT, bsums, n);
        bucket_place<<<NB_adj, 256, 0, stream>>>(
            adj_rows, adj_cols, adj_vals, e_adj, NB_adj, histT, rec);
        bucket_finalize<<<NBUCK, 1024, 0, stream>>>(
            rec, e_adj, NB_adj, histT, rpAdj, evAdj);
    }
    // ---- build CSR for img ----
    {
        const int n = NBUCK * NB_img;
        const int nsb = (n + 1023) / 1024;
        bucket_count<<<NB_img, 256, 0, stream>>>(img_rows, e_img, NB_img, histT);
        scanA<<<nsb, 1024, 0, stream>>>(histT, histT, bsums, n);
        scanB<<<1, 1024, 0, stream>>>(bsums, nsb);
        scan_apply<<<(n + 255) / 256, 256, 0, stream>>>(histT, bsums, n);
        bucket_place<<<NB_img, 256, 0, stream>>>(
            img_rows, img_cols, img_vals, e_img, NB_img, histT, rec);
        bucket_finalize<<<NBUCK, 1024, 0, stream>>>(
            rec, e_img, NB_img, histT, rpImg, evImg);
    }

    const int SPMM8_GRID = (NN + 31) / 32;   // 4 waves/block, 8 rows/wave
    const int SPMM_GRID = (NN * 64 + 255) / 256;
    const int RN_GRID = (ITEM_N * 64 + 255) / 256;

    if (use_h) {
        __half* x0I = x0 + (size_t)USER_N * D;
        __half* xBI = xB + (size_t)USER_N * D;

        // x0 = [u16; i16]
        cvt_f2h<<<(USER_N * D / 4 + 255) / 256, 256, 0, stream>>>(
            uEmb, x0, USER_N * D / 4);
        cvt_f2h<<<(ITEM_N * D / 4 + 255) / 256, 256, 0, stream>>>(
            iEmb, x0I, ITEM_N * D / 4);

        // g = img_adj @ [u;i] -> bufA     (last reader of evImg)
        spmm_h8<<<SPMM8_GRID, 256, 0, stream>>>(
            rpImg, evImg, x0, bufA, nullptr, 0, nullptr, nullptr);

        // feats via MFMA; x0 item half <- normalized feats
        wt_prep<<<(D * IMGD + 255) / 256, 256, 0, stream>>>(Wt, wt16);
        gemm_mfma2<<<(ITEM_N + 31) / 32, 256, 0, stream>>>(img_emb, wt16, bt, featsN);
        rownorm_h<<<RN_GRID, 256, 0, stream>>>(featsN, x0I, ITEM_N);

        // xB item half <- i16 (evImg region now dead)
        cvt_f2h<<<(ITEM_N * D / 4 + 255) / 256, 256, 0, stream>>>(
            iEmb, xBI, ITEM_N * D / 4);

        // e1 = adj @ x0 -> bufB; fp16 user rows -> xB  (xB = [e1_U; i16])
        spmm_h8<<<SPMM8_GRID, 256, 0, stream>>>(
            rpAdj, evAdj, x0, bufB, xB, USER_N, nullptr, nullptr);

        // E = adj @ xB + e1 + g -> bufA; fp16 -> xC
        spmm_h8<<<SPMM8_GRID, 256, 0, stream>>>(
            rpAdj, evAdj, xB, bufA, xC, NN, bufB, bufA);

        // cur1 = adj @ xC -> bufB; fp16 -> x0
        spmm_h8<<<SPMM8_GRID, 256, 0, stream>>>(
            rpAdj, evAdj, xC, bufB, x0, NN, nullptr, nullptr);

        // out = adj @ x0 + E + cur1
        spmm_h8<<<SPMM8_GRID, 256, 0, stream>>>(
            rpAdj, evAdj, x0, out, nullptr, 0, bufA, bufB);
    } else {
        gemm_feats32<<<(ITEM_N + 31) / 32, 256, 0, stream>>>(img_emb, Wt, bt, featsN);
        rownorm<<<RN_GRID, 256, 0, stream>>>(featsN, ITEM_N);

        spmm_csr<<<SPMM_GRID, 256, 0, stream>>>(
            rpImg, evImg, uEmb, iEmb, bufA, nullptr, nullptr);
        spmm_csr<<<SPMM_GRID, 256, 0, stream>>>(
            rpAdj, evAdj, uEmb, featsN, bufB, nullptr, nullptr);
        spmm_csr<<<SPMM_GRID, 256, 0, stream>>>(
            rpAdj, evAdj, bufB, iEmb, bufA, bufB, bufA);
        spmm_csr<<<SPMM_GRID, 256, 0, stream>>>(
            rpAdj, evAdj, bufA, bufA + (size_t)USER_N * D, bufB, nullptr, nullptr);
        spmm_csr<<<SPMM_GRID, 256, 0, stream>>>(
            rpAdj, evAdj, bufB, bufB + (size_t)USER_N * D, out, bufA, bufB);
    }
}